// Round 8
// baseline (518.759 us; speedup 1.0000x reference)
//
#include <hip/hip_runtime.h>
#include <math.h>

#define DIM 128
#define NA 8192
#define CAP 64
#define NF (NA*DIM)

// ---------- shared helpers ----------

// 512-thr gemm over 32 LDS rows (stride 132): out = relu(As @ W^T + bias).
// W (row-major [k][j], 128x128) staged into Ws (64x128) in two halves.
__device__ __forceinline__ void d_gemm32(int tid, const float* As, float* Ws,
    const float* __restrict__ W, const float* __restrict__ bias,
    float* __restrict__ out, int ostr, size_t obase) {
  int rg = tid >> 5, j0 = (tid & 31) * 4;
  float acc[2][4];
  float4 b4 = *(const float4*)&bias[j0];
  #pragma unroll
  for (int rr = 0; rr < 2; ++rr) {
    acc[rr][0] = b4.x; acc[rr][1] = b4.y; acc[rr][2] = b4.z; acc[rr][3] = b4.w;
  }
  #pragma unroll
  for (int half = 0; half < 2; ++half) {
    __syncthreads();
    for (int i = tid; i < 2048; i += 512)
      ((float4*)Ws)[i] = ((const float4*)(W + half * 64 * DIM))[i];
    __syncthreads();
    for (int k4 = 0; k4 < 16; ++k4) {
      float a0[4], a1[4];
      *(float4*)a0 = *(const float4*)&As[(rg * 2) * 132 + half * 64 + k4 * 4];
      *(float4*)a1 = *(const float4*)&As[(rg * 2 + 1) * 132 + half * 64 + k4 * 4];
      #pragma unroll
      for (int kk = 0; kk < 4; ++kk) {
        float4 w4 = *(const float4*)&Ws[(k4 * 4 + kk) * DIM + j0];
        float w[4] = {w4.x, w4.y, w4.z, w4.w};
        #pragma unroll
        for (int c = 0; c < 4; ++c) {
          acc[0][c] += a0[kk] * w[c];
          acc[1][c] += a1[kk] * w[c];
        }
      }
    }
  }
  #pragma unroll
  for (int rr = 0; rr < 2; ++rr) {
    float4 o;
    o.x = fmaxf(acc[rr][0], 0.f); o.y = fmaxf(acc[rr][1], 0.f);
    o.z = fmaxf(acc[rr][2], 0.f); o.w = fmaxf(acc[rr][3], 0.f);
    *(float4*)&out[(obase + rg * 2 + rr) * (size_t)ostr + j0] = o;
  }
}

// 512-thr 23x23 conv over U[54][156] -> relu -> Ao[32][132]
__device__ __forceinline__ void d_conv512(int tid, const float* U, const float* wl,
                                          float cbias, float* Ao) {
  int ro = tid >> 4, d0 = (tid & 15) * 8;
  float a8[8];
  #pragma unroll
  for (int m = 0; m < 8; ++m) a8[m] = 0.f;
  for (int a = 0; a < 23; ++a) {
    float r[30];
    #pragma unroll
    for (int q = 0; q < 7; ++q)
      *(float4*)&r[4 * q] = *(const float4*)&U[(ro + a) * 156 + d0 + 4 * q];
    r[28] = U[(ro + a) * 156 + d0 + 28];
    r[29] = U[(ro + a) * 156 + d0 + 29];
    #pragma unroll
    for (int bb = 0; bb < 23; ++bb) {
      float wb = wl[a * 23 + bb];
      #pragma unroll
      for (int m = 0; m < 8; ++m) a8[m] += r[bb + m] * wb;
    }
  }
  #pragma unroll
  for (int m = 0; m < 8; ++m)
    Ao[ro * 132 + d0 + m] = fmaxf(a8[m] + cbias, 0.f);
}

// stage conv tile (54x156, zero-padded) + conv weights
__device__ __forceinline__ void d_tile512(int blk, int tid, const float* __restrict__ src,
                                          const float* __restrict__ cwl,
                                          float* U, float* wl) {
  for (int i = tid; i < 529; i += 512) wl[i] = cwl[i];
  int l0 = blk * 32;
  for (int i = tid; i < 54 * 156; i += 512) {
    int ll = i / 156, dd = i % 156;
    int gl = l0 - 11 + ll, gd = dd - 11;
    float v = 0.f;
    if (gl >= 0 && gl < NA && (unsigned)gd < DIM)
      v = src[(size_t)gl * DIM + gd];
    U[i] = v;
  }
}

// tanh-attention weights for all 54 halo rows, then scale rows in place
__device__ __forceinline__ void d_halo_attn(int tid, float* U, const float* xrow,
                                            float* w54) {
  int wv = tid >> 6, lane = tid & 63;
  for (int ll = wv; ll < 54; ll += 8) {
    float p = U[ll * 156 + 11 + lane * 2] * xrow[lane * 2]
            + U[ll * 156 + 12 + lane * 2] * xrow[lane * 2 + 1];
    #pragma unroll
    for (int s = 32; s > 0; s >>= 1) p += __shfl_xor(p, s, 64);
    if (lane == 0) w54[ll] = tanhf(p);
  }
  __syncthreads();
  for (int i = tid; i < 54 * 128; i += 512) {
    int ll = i >> 7, dd = i & 127;
    U[ll * 156 + 11 + dd] *= w54[ll];
  }
}

// spmv one row per wave: a2 = xs[row] + sum_nbr hs[j]; -> LDS row (+ optional xs writeback)
__device__ __forceinline__ void d_spmv_row(size_t row, int lane,
    const int* __restrict__ ell, const int* __restrict__ cnt,
    const float* __restrict__ hs, float* __restrict__ xs, float* AsRow, int wb) {
  int n = cnt[row];
  const int* er = ell + row * CAP;
  float2 a2 = *(const float2*)&xs[row * DIM + lane * 2];
  int t = 0;
  for (; t + 4 <= n; t += 4) {
    int j0 = er[t], j1 = er[t + 1], j2 = er[t + 2], j3 = er[t + 3];
    float2 h0 = *(const float2*)&hs[(size_t)j0 * DIM + lane * 2];
    float2 h1 = *(const float2*)&hs[(size_t)j1 * DIM + lane * 2];
    float2 h2 = *(const float2*)&hs[(size_t)j2 * DIM + lane * 2];
    float2 h3 = *(const float2*)&hs[(size_t)j3 * DIM + lane * 2];
    a2.x += (h0.x + h1.x) + (h2.x + h3.x);
    a2.y += (h0.y + h1.y) + (h2.y + h3.y);
  }
  for (; t < n; ++t) {
    float2 h = *(const float2*)&hs[(size_t)er[t] * DIM + lane * 2];
    a2.x += h.x; a2.y += h.y;
  }
  if (wb) *(float2*)&xs[row * DIM + lane * 2] = a2;
  AsRow[lane * 2] = a2.x;
  AsRow[lane * 2 + 1] = a2.y;
}

// ---------- k1: prep (gathers + transposes + zero degcol/ctrs) ----------
__global__ __launch_bounds__(256) void k_prep(
    const int* __restrict__ fp, const int* __restrict__ words,
    const float* __restrict__ emb_fp, const float* __restrict__ emb_w,
    const float* __restrict__ Wg, const float* __restrict__ Wa,
    float* __restrict__ xs, float* __restrict__ xsp,
    float* __restrict__ WgT, float* __restrict__ WaT,
    int* __restrict__ degcol, int* __restrict__ ctrs) {
  int b = blockIdx.x, tid = threadIdx.x;
  if (b < 1024) {
    int i = b * 256 + tid;
    int row = i >> 5, c4 = i & 31;
    ((float4*)(xs + (size_t)row * DIM))[c4] =
        ((const float4*)(emb_fp + (size_t)fp[row] * DIM))[c4];
  } else if (b < 2048) {
    int i = (b - 1024) * 256 + tid;
    int row = i >> 5, c4 = i & 31;
    ((float4*)(xsp + (size_t)row * DIM))[c4] =
        ((const float4*)(emb_w + (size_t)words[row] * DIM))[c4];
  } else if (b < 2112) {
    __shared__ float tile[32][33];
    int sub = b - 2048;
    int m = sub >> 4, t = sub & 15;
    int tx = t & 3, ty = t >> 2;
    const float* src = (m < 3) ? Wg + m * DIM * DIM : Wa;
    float*       dst = (m < 3) ? WgT + m * DIM * DIM : WaT;
    int x = tid & 31, y0 = tid >> 5;
    int xg = tx * 32 + x;
    for (int i = y0; i < 32; i += 8)
      tile[i][x] = src[(ty * 32 + i) * DIM + xg];
    __syncthreads();
    int xo = ty * 32 + x;
    for (int i = y0; i < 32; i += 8)
      dst[(tx * 32 + i) * DIM + xo] = tile[x][i];
  } else if (b < 2120) {                // zero degcol: 8 blocks x 256 x int4
    int i = (b - 2112) * 256 + tid;
    int4 z; z.x = 0; z.y = 0; z.z = 0; z.w = 0;
    ((int4*)degcol)[i] = z;
  } else {
    if (tid == 0) { ctrs[0] = 0; ctrs[1] = 0; }
  }
}

// ---------- k2: ELL + degcol scan (HBM floor) ----------
__global__ __launch_bounds__(256) void k_ell(const float* __restrict__ adj,
                                             int* __restrict__ ell, int* __restrict__ cnt,
                                             int* __restrict__ degcol) {
  int wv = threadIdx.x >> 6, lane = threadIdx.x & 63;
  int row = blockIdx.x * 4 + wv;
  const float4* rp = (const float4*)(adj + (size_t)row * NA);
  int* er = ell + (size_t)row * CAP;
  int c = 0;
  float4 buf[8];
  #pragma unroll
  for (int u = 0; u < 8; ++u) buf[u] = rp[u * 64 + lane];
  for (int it = 0; it < 32; it += 8) {
    float4 nb[8];
    if (it + 8 < 32) {
      #pragma unroll
      for (int u = 0; u < 8; ++u) nb[u] = rp[(it + 8 + u) * 64 + lane];
    }
    #pragma unroll
    for (int u = 0; u < 8; ++u) {
      float f[4] = {buf[u].x, buf[u].y, buf[u].z, buf[u].w};
      #pragma unroll
      for (int j = 0; j < 4; ++j) {
        bool nz = (f[j] != 0.0f);
        unsigned long long m = __ballot(nz);
        if (nz) {
          int col = (it + u) * 256 + lane * 4 + j;
          int pos = c + __popcll(m & ((1ull << lane) - 1ull));
          if (pos < CAP) er[pos] = col;
          atomicAdd(&degcol[col], 1);
        }
        c += __popcll(m);
      }
    }
    #pragma unroll
    for (int u = 0; u < 8; ++u) buf[u] = nb[u];
  }
  if (lane == 0) cnt[row] = c > CAP ? CAP : c;
}

// ---------- k3: heads — GNN gemm0 (b<256) + protein conv0/gemm0 (b>=256) ----------
__global__ __launch_bounds__(512) void k_heads(
    const float* __restrict__ xs, const float* __restrict__ WgT0,
    const float* __restrict__ bg0, float* __restrict__ hs0,
    const float* __restrict__ xsp0, const float* __restrict__ cw0,
    const float* __restrict__ cb0, const float* __restrict__ WaT,
    const float* __restrict__ ba, float* __restrict__ hs2p0) {
  __shared__ float S[13184];
  int b = blockIdx.x, tid = threadIdx.x;
  if (b < 256) {
    float* As = S;            // 32*132
    float* Ws = S + 4224;     // 64*128
    size_t rbase = (size_t)b * 32;
    for (int i = tid; i < 1024; i += 512) {
      int r = i >> 5, c = i & 31;
      *(float4*)&As[r * 132 + c * 4] = *(const float4*)&xs[(rbase + r) * DIM + c * 4];
    }
    d_gemm32(tid, As, Ws, WgT0, bg0, hs0, DIM, rbase);
  } else {
    int blk = b - 256;
    float* U  = S;            // 8424 (Ws reuse: 8192)
    float* wl = S + 8424;     // 529
    float* Ao = S + 8960;     // 4224
    d_tile512(blk, tid, xsp0, cw0, U, wl);
    __syncthreads();
    d_conv512(tid, U, wl, cb0[0], Ao);
    d_gemm32(tid, Ao, U, WaT, ba, hs2p0, DIM, (size_t)blk * 32);
  }
}

// ---------- k4: spmv0 + gemm1 -> hs1 (1024 x 512, 8 rows/block) ----------
__global__ __launch_bounds__(512) void k_g1(
    const int* __restrict__ ell, const int* __restrict__ cnt,
    const float* __restrict__ hs0, float* __restrict__ xs,
    const float* __restrict__ WgT1, const float* __restrict__ bg1,
    float* __restrict__ hs1) {
  __shared__ float As[8 * 132];
  __shared__ float Ws[64 * 128];
  int tid = threadIdx.x;
  int wv = tid >> 6, lane = tid & 63;
  size_t rbase = (size_t)blockIdx.x * 8;
  d_spmv_row(rbase + wv, lane, ell, cnt, hs0, xs, &As[wv * 132], 1);
  // gemm1: thread -> row wv, cols c0..c0+1
  int c0 = lane * 2;
  float acc0 = bg1[c0], acc1 = bg1[c0 + 1];
  #pragma unroll
  for (int half = 0; half < 2; ++half) {
    __syncthreads();
    for (int i = tid; i < 2048; i += 512)
      ((float4*)Ws)[i] = ((const float4*)(WgT1 + half * 64 * DIM))[i];
    __syncthreads();
    for (int k = 0; k < 64; ++k) {
      float av = As[wv * 132 + half * 64 + k];
      float2 w2 = *(const float2*)&Ws[k * DIM + c0];
      acc0 += av * w2.x;
      acc1 += av * w2.y;
    }
  }
  float2 o;
  o.x = fmaxf(acc0, 0.f); o.y = fmaxf(acc1, 0.f);
  *(float2*)&hs1[(rbase + wv) * DIM + c0] = o;
}

// ---------- k5: spmv1 + gemm2 + deg-weighted partial; last block: reduce + xchain ----------
__global__ __launch_bounds__(512) void k_g2(
    const int* __restrict__ ell, const int* __restrict__ cnt,
    const float* __restrict__ hs1, const float* __restrict__ xs,
    const float* __restrict__ WgT2, const float* __restrict__ bg2,
    const int* __restrict__ degcol, float* __restrict__ partialG,
    float* __restrict__ xc, const float* __restrict__ WaT,
    const float* __restrict__ ba, float* __restrict__ xall,
    int* __restrict__ ctr) {
  __shared__ float As[8 * 132];
  __shared__ float H2[8 * 132];
  __shared__ float Ws[64 * 128];
  __shared__ float red[4 * DIM];
  __shared__ float xb[DIM];
  __shared__ int lastf;
  int tid = threadIdx.x;
  int wv = tid >> 6, lane = tid & 63;
  size_t rbase = (size_t)blockIdx.x * 8;
  d_spmv_row(rbase + wv, lane, ell, cnt, hs1, (float*)xs, &As[wv * 132], 0);
  int c0 = lane * 2;
  float acc0 = bg2[c0], acc1 = bg2[c0 + 1];
  #pragma unroll
  for (int half = 0; half < 2; ++half) {
    __syncthreads();
    for (int i = tid; i < 2048; i += 512)
      ((float4*)Ws)[i] = ((const float4*)(WgT2 + half * 64 * DIM))[i];
    __syncthreads();
    for (int k = 0; k < 64; ++k) {
      float av = As[wv * 132 + half * 64 + k];
      float2 w2 = *(const float2*)&Ws[k * DIM + c0];
      acc0 += av * w2.x;
      acc1 += av * w2.y;
    }
  }
  H2[wv * 132 + c0]     = fmaxf(acc0, 0.f);
  H2[wv * 132 + c0 + 1] = fmaxf(acc1, 0.f);
  __syncthreads();
  // partial[c] = sum_r xs2[r][c] + deg[r]*hs2[r][c]
  if (tid < DIM) {
    float s = 0.f;
    #pragma unroll
    for (int r = 0; r < 8; ++r) {
      float dg = (float)degcol[rbase + r];
      s += As[r * 132 + tid] + dg * H2[r * 132 + tid];
    }
    partialG[blockIdx.x * DIM + tid] = s;
  }
  __threadfence();
  __syncthreads();
  if (tid == 0) lastf = (atomicAdd(ctr, 1) == (int)gridDim.x - 1);
  __syncthreads();
  if (lastf) {
    __threadfence();
    // reduce 1024 partials
    {
      int c = tid & 127, q = tid >> 7;
      float s = 0.f;
      for (int bb = q * 256; bb < q * 256 + 256; bb += 4) {
        s += partialG[(bb + 0) * DIM + c] + partialG[(bb + 1) * DIM + c]
           + partialG[(bb + 2) * DIM + c] + partialG[(bb + 3) * DIM + c];
      }
      red[q * DIM + c] = s;
    }
    __syncthreads();
    if (tid < DIM) {
      float v = red[tid] + red[DIM + tid] + red[2 * DIM + tid] + red[3 * DIM + tid];
      xc[tid] = v;
      xb[tid] = v;
    }
    __syncthreads();
    for (int i = 0; i < 3; ++i) {
      float a = 0.f;
      if (tid < DIM) {
        a = ba[tid];
        for (int k = 0; k < DIM; ++k) a += xb[k] * WaT[k * DIM + tid];
        a = fmaxf(a, 0.f);
      }
      __syncthreads();
      if (tid < DIM) { xb[tid] = a; xall[i * DIM + tid] = a; }
      __syncthreads();
    }
  }
}

// ---------- k6: protein layer1: attn0 + conv1 + gemm1 -> hs2p1 ----------
__global__ __launch_bounds__(512) void k_p1(
    const float* __restrict__ hs2p0, const float* __restrict__ xall,
    const float* __restrict__ cw1, const float* __restrict__ cb1,
    const float* __restrict__ WaT, const float* __restrict__ ba,
    float* __restrict__ hs2p1) {
  __shared__ float U[54 * 156];
  __shared__ float wl[529];
  __shared__ float Ao[32 * 132];
  __shared__ float w54[56];
  __shared__ float xrow[DIM];
  int tid = threadIdx.x, blk = blockIdx.x;
  if (tid < DIM) xrow[tid] = xall[tid];
  d_tile512(blk, tid, hs2p0, cw1, U, wl);
  __syncthreads();
  d_halo_attn(tid, U, xrow, w54);
  __syncthreads();
  d_conv512(tid, U, wl, cb1[0], Ao);
  d_gemm32(tid, Ao, U, WaT, ba, hs2p1, DIM, (size_t)blk * 32);
}

// ---------- k7: protein layer2: attn1 + conv2 + gemm2 + attn2-partial; last: reduce + final ----------
__global__ __launch_bounds__(512) void k_p2(
    const float* __restrict__ hs2p1, const float* __restrict__ xall,
    const float* __restrict__ cw2, const float* __restrict__ cb2,
    const float* __restrict__ WaT, const float* __restrict__ ba,
    float* __restrict__ partialP, const float* __restrict__ xc,
    const float* __restrict__ Wo, const float* __restrict__ bo,
    float* __restrict__ out, int* __restrict__ ctr) {
  __shared__ float U[54 * 156];
  __shared__ float wl[529];
  __shared__ float Ao[32 * 132];
  __shared__ float H2[32 * 132];
  __shared__ float w54[56];
  __shared__ float xrow[DIM];
  __shared__ float red[4 * DIM];
  __shared__ float xps[DIM];
  __shared__ float fs[32];
  __shared__ int lastf;
  int tid = threadIdx.x, blk = blockIdx.x;
  int wv = tid >> 6, lane = tid & 63;
  if (tid < DIM) xrow[tid] = xall[DIM + tid];       // x_1
  d_tile512(blk, tid, hs2p1, cw2, U, wl);
  __syncthreads();
  d_halo_attn(tid, U, xrow, w54);
  __syncthreads();
  d_conv512(tid, U, wl, cb2[0], Ao);
  d_gemm32(tid, Ao, U, WaT, ba, H2, 132, 0);        // hs2 of layer2 -> LDS
  __syncthreads();
  // attn2 weights with x_2 for own 32 rows
  {
    float x0 = xall[2 * DIM + lane * 2], x1 = xall[2 * DIM + lane * 2 + 1];
    for (int rr = 0; rr < 4; ++rr) {
      int row = wv * 4 + rr;
      float2 h = *(const float2*)&H2[row * 132 + lane * 2];
      float p = h.x * x0 + h.y * x1;
      #pragma unroll
      for (int s = 32; s > 0; s >>= 1) p += __shfl_xor(p, s, 64);
      if (lane == 0) w54[row] = tanhf(p);
    }
  }
  __syncthreads();
  if (tid < DIM) {
    float s = 0.f;
    #pragma unroll
    for (int r = 0; r < 32; ++r) s += w54[r] * H2[r * 132 + tid];
    partialP[blk * DIM + tid] = s;
  }
  __threadfence();
  __syncthreads();
  if (tid == 0) lastf = (atomicAdd(ctr, 1) == (int)gridDim.x - 1);
  __syncthreads();
  if (lastf) {
    __threadfence();
    {
      int c = tid & 127, q = tid >> 7;
      float s = 0.f;
      for (int bb = q * 64; bb < q * 64 + 64; bb += 4) {
        s += partialP[(bb + 0) * DIM + c] + partialP[(bb + 1) * DIM + c]
           + partialP[(bb + 2) * DIM + c] + partialP[(bb + 3) * DIM + c];
      }
      red[q * DIM + c] = s;
    }
    __syncthreads();
    if (tid < DIM)
      xps[tid] = red[tid] + red[DIM + tid] + red[2 * DIM + tid] + red[3 * DIM + tid];
    __syncthreads();
    float p0 = 0.f, p1 = 0.f;
    if (tid < 256) {
      float y = (tid < DIM) ? xc[tid] : xps[tid - DIM];
      p0 = y * Wo[tid];
      p1 = y * Wo[256 + tid];
    }
    #pragma unroll
    for (int s = 32; s > 0; s >>= 1) {
      p0 += __shfl_xor(p0, s, 64);
      p1 += __shfl_xor(p1, s, 64);
    }
    if (tid < 256 && lane == 0) { fs[wv] = p0; fs[16 + wv] = p1; }
    __syncthreads();
    if (tid == 0) {
      float l0 = bo[0], l1 = bo[1];
      #pragma unroll
      for (int w = 0; w < 4; ++w) { l0 += fs[w]; l1 += fs[16 + w]; }
      float m = fmaxf(l0, l1);
      float e0 = expf(l0 - m), e1 = expf(l1 - m);
      out[0] = e0 / (e0 + e1);
      out[1] = e1 / (e0 + e1);
    }
  }
}

// ---------- host ----------
extern "C" void kernel_launch(void* const* d_in, const int* in_sizes, int n_in,
                              void* d_out, int out_size, void* d_ws, size_t ws_size,
                              hipStream_t stream) {
  const int*   fp     = (const int*)d_in[0];
  const int*   words  = (const int*)d_in[1];
  const float* adj    = (const float*)d_in[2];
  const float* emb_fp = (const float*)d_in[3];
  const float* emb_w  = (const float*)d_in[4];
  const float* Wg     = (const float*)d_in[5];
  const float* bg     = (const float*)d_in[6];
  const float* cw     = (const float*)d_in[7];
  const float* cb     = (const float*)d_in[8];
  const float* Wa     = (const float*)d_in[9];
  const float* ba     = (const float*)d_in[10];
  const float* Wo     = (const float*)d_in[11];
  const float* bo     = (const float*)d_in[12];
  float* out = (float*)d_out;

  float* ws    = (float*)d_ws;
  float* xs    = ws;                      // atom features (updated in place)
  float* bufB  = ws + (size_t)NF;         // hs0, then hs2p1
  float* bufC  = ws + 2 * (size_t)NF;     // xsp0, then hs1
  float* bufD  = ws + 3 * (size_t)NF;     // hs2p0
  int*   ell   = (int*)(ws + 4 * (size_t)NF);
  int*   cnt   = ell + (size_t)NA * CAP;
  int*   degcol= cnt + NA;
  int*   ctrs  = degcol + NA;             // [2]
  float* xc    = (float*)(ctrs + 2);      // [128]
  float* xall  = xc + DIM;                // [3,128]
  float* WgT   = xall + 3 * DIM;          // [3,128,128]
  float* WaT   = WgT + 3 * DIM * DIM;     // [128,128]
  float* partG = WaT + DIM * DIM;         // [1024,128]
  float* partP = partG + 1024 * DIM;      // [64? -> 256,128]

  k_prep<<<dim3(2121), 256, 0, stream>>>(fp, words, emb_fp, emb_w, Wg, Wa,
                                         xs, bufC, WgT, WaT, degcol, ctrs);
  k_ell<<<dim3(NA / 4), 256, 0, stream>>>(adj, ell, cnt, degcol);
  k_heads<<<dim3(512), 512, 0, stream>>>(xs, WgT, bg, bufB,
                                         bufC, cw, cb, WaT, ba, bufD);
  k_g1<<<dim3(1024), 512, 0, stream>>>(ell, cnt, bufB, xs,
                                       WgT + (size_t)DIM * DIM, bg + DIM, bufC);
  k_g2<<<dim3(1024), 512, 0, stream>>>(ell, cnt, bufC, xs,
                                       WgT + 2 * (size_t)DIM * DIM, bg + 2 * DIM,
                                       degcol, partG, xc, WaT, ba, xall, ctrs);
  k_p1<<<dim3(256), 512, 0, stream>>>(bufD, xall, cw + 529, cb + 1, WaT, ba, bufB);
  k_p2<<<dim3(256), 512, 0, stream>>>(bufB, xall, cw + 2 * 529, cb + 2, WaT, ba,
                                      partP, xc, Wo, bo, out, ctrs + 1);
}

// Round 9
// 378.713 us; speedup vs baseline: 1.3698x; 1.3698x over previous
//
#include <hip/hip_runtime.h>
#include <math.h>

#define DIM 128
#define NA 8192
#define CAP 64
#define NF (NA*DIM)

// ================= proven helpers =================

// 512-thr gemm over 32 LDS rows (stride 132): out = relu(As @ W^T + bias).
// W staged into Ws (64x128) in two halves. [proven r8: k_heads/k_p1/k_p2]
__device__ __forceinline__ void d_gemm32(int tid, const float* As, float* Ws,
    const float* __restrict__ W, const float* __restrict__ bias,
    float* __restrict__ out, int ostr, size_t obase) {
  int rg = tid >> 5, j0 = (tid & 31) * 4;
  float acc[2][4];
  float4 b4 = *(const float4*)&bias[j0];
  #pragma unroll
  for (int rr = 0; rr < 2; ++rr) {
    acc[rr][0] = b4.x; acc[rr][1] = b4.y; acc[rr][2] = b4.z; acc[rr][3] = b4.w;
  }
  #pragma unroll
  for (int half = 0; half < 2; ++half) {
    __syncthreads();
    for (int i = tid; i < 2048; i += 512)
      ((float4*)Ws)[i] = ((const float4*)(W + half * 64 * DIM))[i];
    __syncthreads();
    for (int k4 = 0; k4 < 16; ++k4) {
      float a0[4], a1[4];
      *(float4*)a0 = *(const float4*)&As[(rg * 2) * 132 + half * 64 + k4 * 4];
      *(float4*)a1 = *(const float4*)&As[(rg * 2 + 1) * 132 + half * 64 + k4 * 4];
      #pragma unroll
      for (int kk = 0; kk < 4; ++kk) {
        float4 w4 = *(const float4*)&Ws[(k4 * 4 + kk) * DIM + j0];
        float w[4] = {w4.x, w4.y, w4.z, w4.w};
        #pragma unroll
        for (int c = 0; c < 4; ++c) {
          acc[0][c] += a0[kk] * w[c];
          acc[1][c] += a1[kk] * w[c];
        }
      }
    }
  }
  #pragma unroll
  for (int rr = 0; rr < 2; ++rr) {
    float4 o;
    o.x = fmaxf(acc[rr][0], 0.f); o.y = fmaxf(acc[rr][1], 0.f);
    o.z = fmaxf(acc[rr][2], 0.f); o.w = fmaxf(acc[rr][3], 0.f);
    *(float4*)&out[(obase + rg * 2 + rr) * (size_t)ostr + j0] = o;
  }
}

// 512-thr 23x23 conv over U[54][156] -> relu -> Ao[32][132] [proven r8]
__device__ __forceinline__ void d_conv512(int tid, const float* U, const float* wl,
                                          float cbias, float* Ao) {
  int ro = tid >> 4, d0 = (tid & 15) * 8;
  float a8[8];
  #pragma unroll
  for (int m = 0; m < 8; ++m) a8[m] = 0.f;
  for (int a = 0; a < 23; ++a) {
    float r[30];
    #pragma unroll
    for (int q = 0; q < 7; ++q)
      *(float4*)&r[4 * q] = *(const float4*)&U[(ro + a) * 156 + d0 + 4 * q];
    r[28] = U[(ro + a) * 156 + d0 + 28];
    r[29] = U[(ro + a) * 156 + d0 + 29];
    #pragma unroll
    for (int bb = 0; bb < 23; ++bb) {
      float wb = wl[a * 23 + bb];
      #pragma unroll
      for (int m = 0; m < 8; ++m) a8[m] += r[bb + m] * wb;
    }
  }
  #pragma unroll
  for (int m = 0; m < 8; ++m)
    Ao[ro * 132 + d0 + m] = fmaxf(a8[m] + cbias, 0.f);
}

// stage conv tile (54x156, zero-padded) + conv weights [proven r8]
__device__ __forceinline__ void d_tile512(int blk, int tid, const float* __restrict__ src,
                                          const float* __restrict__ cwl,
                                          float* U, float* wl) {
  for (int i = tid; i < 529; i += 512) wl[i] = cwl[i];
  int l0 = blk * 32;
  for (int i = tid; i < 54 * 156; i += 512) {
    int ll = i / 156, dd = i % 156;
    int gl = l0 - 11 + ll, gd = dd - 11;
    float v = 0.f;
    if (gl >= 0 && gl < NA && (unsigned)gd < DIM)
      v = src[(size_t)gl * DIM + gd];
    U[i] = v;
  }
}

// halo attention: tanh weights for 54 rows then scale rows in place [proven r8]
__device__ __forceinline__ void d_halo_attn(int tid, float* U, const float* xrow,
                                            float* w54) {
  int wv = tid >> 6, lane = tid & 63;
  for (int ll = wv; ll < 54; ll += 8) {
    float p = U[ll * 156 + 11 + lane * 2] * xrow[lane * 2]
            + U[ll * 156 + 12 + lane * 2] * xrow[lane * 2 + 1];
    #pragma unroll
    for (int s = 32; s > 0; s >>= 1) p += __shfl_xor(p, s, 64);
    if (lane == 0) w54[ll] = tanhf(p);
  }
  __syncthreads();
  for (int i = tid; i < 54 * 128; i += 512) {
    int ll = i >> 7, dd = i & 127;
    U[ll * 156 + 11 + dd] *= w54[ll];
  }
}

// ================= k1: prep [proven r3/r8] =================
__global__ __launch_bounds__(256) void k_prep(
    const int* __restrict__ fp, const int* __restrict__ words,
    const float* __restrict__ emb_fp, const float* __restrict__ emb_w,
    const float* __restrict__ Wg, const float* __restrict__ Wa,
    float* __restrict__ xs, float* __restrict__ xsp,
    float* __restrict__ WgT, float* __restrict__ WaT,
    int* __restrict__ degcol, int* __restrict__ ctrs) {
  int b = blockIdx.x, tid = threadIdx.x;
  if (b < 1024) {
    int i = b * 256 + tid;
    int row = i >> 5, c4 = i & 31;
    ((float4*)(xs + (size_t)row * DIM))[c4] =
        ((const float4*)(emb_fp + (size_t)fp[row] * DIM))[c4];
  } else if (b < 2048) {
    int i = (b - 1024) * 256 + tid;
    int row = i >> 5, c4 = i & 31;
    ((float4*)(xsp + (size_t)row * DIM))[c4] =
        ((const float4*)(emb_w + (size_t)words[row] * DIM))[c4];
  } else if (b < 2112) {
    __shared__ float tile[32][33];
    int sub = b - 2048;
    int m = sub >> 4, t = sub & 15;
    int tx = t & 3, ty = t >> 2;
    const float* src = (m < 3) ? Wg + m * DIM * DIM : Wa;
    float*       dst = (m < 3) ? WgT + m * DIM * DIM : WaT;
    int x = tid & 31, y0 = tid >> 5;
    int xg = tx * 32 + x;
    for (int i = y0; i < 32; i += 8)
      tile[i][x] = src[(ty * 32 + i) * DIM + xg];
    __syncthreads();
    int xo = ty * 32 + x;
    for (int i = y0; i < 32; i += 8)
      dst[(tx * 32 + i) * DIM + xo] = tile[x][i];
  } else if (b < 2120) {                // zero degcol
    int i = (b - 2112) * 256 + tid;
    int4 z; z.x = 0; z.y = 0; z.z = 0; z.w = 0;
    ((int4*)degcol)[i] = z;
  } else {
    if (tid == 0) { ctrs[0] = 0; ctrs[1] = 0; }
  }
}

// ================= k2: scan = ELL+degcol (HBM floor) + GNN gemm0 + prot conv0/gemm0 =================
__global__ __launch_bounds__(512) void k_scan(
    const float* __restrict__ adj,
    const float* __restrict__ xs, const float* __restrict__ WgT0,
    const float* __restrict__ bg0, float* __restrict__ hs0,
    const float* __restrict__ xsp0, const float* __restrict__ cw0,
    const float* __restrict__ cb0, const float* __restrict__ WaT,
    const float* __restrict__ ba, float* __restrict__ hs2p0,
    int* __restrict__ ell, int* __restrict__ cnt, int* __restrict__ degcol) {
  __shared__ float S[13184];
  int b = blockIdx.x, tid = threadIdx.x;
  if (b < 256) {
    // GNN gemm0 [proven r8 k_heads]
    float* As = S;            // 32*132
    float* Ws = S + 4224;     // 64*128
    size_t rbase = (size_t)b * 32;
    for (int i = tid; i < 1024; i += 512) {
      int r = i >> 5, c = i & 31;
      *(float4*)&As[r * 132 + c * 4] = *(const float4*)&xs[(rbase + r) * DIM + c * 4];
    }
    d_gemm32(tid, As, Ws, WgT0, bg0, hs0, DIM, rbase);
  } else if (b < 512) {
    // protein conv0 + gemm0 [proven r8 k_heads]
    int blk = b - 256;
    float* U  = S;            // 8424 (reused as Ws: 8192)
    float* wl = S + 8424;
    float* Ao = S + 8960;
    d_tile512(blk, tid, xsp0, cw0, U, wl);
    __syncthreads();
    d_conv512(tid, U, wl, cb0[0], Ao);
    d_gemm32(tid, Ao, U, WaT, ba, hs2p0, DIM, (size_t)blk * 32);
  } else {
    // ELL + degcol: 8 waves, 1 row/wave, 8-deep prefetch [proven r7/r8]
    int wv = tid >> 6, lane = tid & 63;
    int row = (b - 512) * 8 + wv;
    const float4* rp = (const float4*)(adj + (size_t)row * NA);
    int* er = ell + (size_t)row * CAP;
    int c = 0;
    float4 buf[8];
    #pragma unroll
    for (int u = 0; u < 8; ++u) buf[u] = rp[u * 64 + lane];
    for (int it = 0; it < 32; it += 8) {
      float4 nb[8];
      if (it + 8 < 32) {
        #pragma unroll
        for (int u = 0; u < 8; ++u) nb[u] = rp[(it + 8 + u) * 64 + lane];
      }
      #pragma unroll
      for (int u = 0; u < 8; ++u) {
        float f[4] = {buf[u].x, buf[u].y, buf[u].z, buf[u].w};
        #pragma unroll
        for (int j = 0; j < 4; ++j) {
          bool nz = (f[j] != 0.0f);
          unsigned long long m = __ballot(nz);
          if (nz) {
            int col = (it + u) * 256 + lane * 4 + j;
            int pos = c + __popcll(m & ((1ull << lane) - 1ull));
            if (pos < CAP) er[pos] = col;
            atomicAdd(&degcol[col], 1);
          }
          c += __popcll(m);
        }
      }
      #pragma unroll
      for (int u = 0; u < 8; ++u) buf[u] = nb[u];
    }
    if (lane == 0) cnt[row] = c > CAP ? CAP : c;
  }
}

// ================= k3: spmv (xs += A@hs), wave/row, no LDS [proven r3] =================
__global__ void k_spmv(const int* __restrict__ ell, const int* __restrict__ cnt,
                       const float* __restrict__ hs, float* __restrict__ xs) {
  int wv = threadIdx.x >> 6, lane = threadIdx.x & 63;
  int row = blockIdx.x * 4 + wv;
  int n = cnt[row];
  const int* er = ell + (size_t)row * CAP;
  float2 acc = *(const float2*)&xs[(size_t)row * DIM + lane * 2];
  int t = 0;
  for (; t + 4 <= n; t += 4) {
    int ja = er[t], jb = er[t + 1], jc = er[t + 2], jd = er[t + 3];
    float2 ha = *(const float2*)&hs[(size_t)ja * DIM + lane * 2];
    float2 hb = *(const float2*)&hs[(size_t)jb * DIM + lane * 2];
    float2 hc = *(const float2*)&hs[(size_t)jc * DIM + lane * 2];
    float2 hd = *(const float2*)&hs[(size_t)jd * DIM + lane * 2];
    acc.x += (ha.x + hb.x) + (hc.x + hd.x);
    acc.y += (ha.y + hb.y) + (hc.y + hd.y);
  }
  for (; t < n; ++t) {
    int j = er[t];
    float2 h = *(const float2*)&hs[(size_t)j * DIM + lane * 2];
    acc.x += h.x; acc.y += h.y;
  }
  *(float2*)&xs[(size_t)row * DIM + lane * 2] = acc;
}

// ================= k4: gemm layer1 [proven r3 k_gemm_g] =================
__global__ __launch_bounds__(256) void k_gemm1(
    const float* __restrict__ A, const float* __restrict__ WT,
    const float* __restrict__ bias, float* __restrict__ C) {
  __shared__ float As[32 * 132];
  __shared__ float Ws[128 * 128];
  int tid = threadIdx.x;
  size_t rbase = (size_t)blockIdx.x * 32;
  int j0 = (tid & 31) * 4, r0 = (tid >> 5) * 4;
  for (int i = tid; i < 4096; i += 256)
    ((float4*)Ws)[i] = ((const float4*)WT)[i];
  for (int i = tid; i < 1024; i += 256) {
    int r = i >> 5, c = i & 31;
    *(float4*)&As[r * 132 + c * 4] = *(const float4*)&A[(rbase + r) * DIM + c * 4];
  }
  __syncthreads();
  float acc[4][4];
  {
    float4 b4 = *(const float4*)&bias[j0];
    #pragma unroll
    for (int ri = 0; ri < 4; ++ri) {
      acc[ri][0] = b4.x; acc[ri][1] = b4.y; acc[ri][2] = b4.z; acc[ri][3] = b4.w;
    }
  }
  for (int k4 = 0; k4 < 32; ++k4) {
    float a[4][4];
    #pragma unroll
    for (int ri = 0; ri < 4; ++ri)
      *(float4*)a[ri] = *(float4*)&As[(r0 + ri) * 132 + k4 * 4];
    #pragma unroll
    for (int kk = 0; kk < 4; ++kk) {
      float4 w4 = *(float4*)&Ws[(k4 * 4 + kk) * DIM + j0];
      float w[4] = {w4.x, w4.y, w4.z, w4.w};
      #pragma unroll
      for (int ri = 0; ri < 4; ++ri)
        #pragma unroll
        for (int c = 0; c < 4; ++c)
          acc[ri][c] += a[ri][kk] * w[c];
    }
  }
  #pragma unroll
  for (int ri = 0; ri < 4; ++ri) {
    float4 o;
    o.x = fmaxf(acc[ri][0], 0.f); o.y = fmaxf(acc[ri][1], 0.f);
    o.z = fmaxf(acc[ri][2], 0.f); o.w = fmaxf(acc[ri][3], 0.f);
    *(float4*)&C[(rbase + r0 + ri) * DIM + j0] = o;
  }
}

// ================= k5: gemm layer2 + deg-weighted partial; last block: reduce + xchain =================
__global__ __launch_bounds__(256) void k_g2fin(
    const float* __restrict__ A, const float* __restrict__ WT,
    const float* __restrict__ bias, const int* __restrict__ degcol,
    float* __restrict__ partial, float* __restrict__ xc,
    const float* __restrict__ WaT, const float* __restrict__ ba,
    float* __restrict__ xall, int* __restrict__ ctr) {
  __shared__ float As[32 * 132];
  __shared__ float Ws[128 * 128];
  __shared__ float red[8 * DIM];
  __shared__ float xb[DIM];
  __shared__ int lastf;
  int tid = threadIdx.x;
  size_t rbase = (size_t)blockIdx.x * 32;
  int j0 = (tid & 31) * 4, r0 = (tid >> 5) * 4;
  for (int i = tid; i < 4096; i += 256)
    ((float4*)Ws)[i] = ((const float4*)WT)[i];
  for (int i = tid; i < 1024; i += 256) {
    int r = i >> 5, c = i & 31;
    *(float4*)&As[r * 132 + c * 4] = *(const float4*)&A[(rbase + r) * DIM + c * 4];
  }
  __syncthreads();
  float acc[4][4];
  {
    float4 b4 = *(const float4*)&bias[j0];
    #pragma unroll
    for (int ri = 0; ri < 4; ++ri) {
      acc[ri][0] = b4.x; acc[ri][1] = b4.y; acc[ri][2] = b4.z; acc[ri][3] = b4.w;
    }
  }
  for (int k4 = 0; k4 < 32; ++k4) {
    float a[4][4];
    #pragma unroll
    for (int ri = 0; ri < 4; ++ri)
      *(float4*)a[ri] = *(float4*)&As[(r0 + ri) * 132 + k4 * 4];
    #pragma unroll
    for (int kk = 0; kk < 4; ++kk) {
      float4 w4 = *(float4*)&Ws[(k4 * 4 + kk) * DIM + j0];
      float w[4] = {w4.x, w4.y, w4.z, w4.w};
      #pragma unroll
      for (int ri = 0; ri < 4; ++ri)
        #pragma unroll
        for (int c = 0; c < 4; ++c)
          acc[ri][c] += a[ri][kk] * w[c];
    }
  }
  // per-thread column partials: sum over its 4 rows of (xs2 + deg*hs2)
  float s4[4];
  #pragma unroll
  for (int jj = 0; jj < 4; ++jj) s4[jj] = 0.f;
  #pragma unroll
  for (int ri = 0; ri < 4; ++ri) {
    float dg = (float)degcol[rbase + r0 + ri];
    #pragma unroll
    for (int jj = 0; jj < 4; ++jj)
      s4[jj] += As[(r0 + ri) * 132 + j0 + jj] + dg * fmaxf(acc[ri][jj], 0.f);
  }
  int rg = tid >> 5;
  #pragma unroll
  for (int jj = 0; jj < 4; ++jj) red[rg * DIM + j0 + jj] = s4[jj];
  __syncthreads();
  if (tid < DIM) {
    float p = 0.f;
    #pragma unroll
    for (int g = 0; g < 8; ++g) p += red[g * DIM + tid];
    partial[blockIdx.x * DIM + tid] = p;
  }
  __threadfence();
  __syncthreads();
  if (tid == 0) lastf = (atomicAdd(ctr, 1) == (int)gridDim.x - 1);
  __syncthreads();
  if (lastf) {
    __threadfence();
    {
      int c = tid & 127, q = tid >> 7;   // 2 chunks x 128 blocks
      float s = 0.f;
      for (int bb = q * 128; bb < q * 128 + 128; bb += 4)
        s += partial[(bb + 0) * DIM + c] + partial[(bb + 1) * DIM + c]
           + partial[(bb + 2) * DIM + c] + partial[(bb + 3) * DIM + c];
      red[q * DIM + c] = s;
    }
    __syncthreads();
    if (tid < DIM) {
      float v = red[tid] + red[DIM + tid];
      xc[tid] = v;
      xb[tid] = v;
    }
    __syncthreads();
    for (int i = 0; i < 3; ++i) {
      float a = 0.f;
      if (tid < DIM) {
        a = ba[tid];
        for (int k = 0; k < DIM; ++k) a += xb[k] * WaT[k * DIM + tid];
        a = fmaxf(a, 0.f);
      }
      __syncthreads();
      if (tid < DIM) { xb[tid] = a; xall[i * DIM + tid] = a; }
      __syncthreads();
    }
  }
}

// ================= k6: protein layer1 [proven r8 k_p1] =================
__global__ __launch_bounds__(512) void k_p1(
    const float* __restrict__ hs2p0, const float* __restrict__ xall,
    const float* __restrict__ cw1, const float* __restrict__ cb1,
    const float* __restrict__ WaT, const float* __restrict__ ba,
    float* __restrict__ hs2p1) {
  __shared__ float U[54 * 156];
  __shared__ float wl[529];
  __shared__ float Ao[32 * 132];
  __shared__ float w54[56];
  __shared__ float xrow[DIM];
  int tid = threadIdx.x, blk = blockIdx.x;
  if (tid < DIM) xrow[tid] = xall[tid];
  d_tile512(blk, tid, hs2p0, cw1, U, wl);
  __syncthreads();
  d_halo_attn(tid, U, xrow, w54);
  __syncthreads();
  d_conv512(tid, U, wl, cb1[0], Ao);
  d_gemm32(tid, Ao, U, WaT, ba, hs2p1, DIM, (size_t)blk * 32);
}

// ================= k7: protein layer2 + partial; last block: reduce + final [proven r8 k_p2] =================
__global__ __launch_bounds__(512) void k_p2(
    const float* __restrict__ hs2p1, const float* __restrict__ xall,
    const float* __restrict__ cw2, const float* __restrict__ cb2,
    const float* __restrict__ WaT, const float* __restrict__ ba,
    float* __restrict__ partialP, const float* __restrict__ xc,
    const float* __restrict__ Wo, const float* __restrict__ bo,
    float* __restrict__ out, int* __restrict__ ctr) {
  __shared__ float U[54 * 156];
  __shared__ float wl[529];
  __shared__ float Ao[32 * 132];
  __shared__ float H2[32 * 132];
  __shared__ float w54[56];
  __shared__ float xrow[DIM];
  __shared__ float red[4 * DIM];
  __shared__ float xps[DIM];
  __shared__ float fs[32];
  __shared__ int lastf;
  int tid = threadIdx.x, blk = blockIdx.x;
  int wv = tid >> 6, lane = tid & 63;
  if (tid < DIM) xrow[tid] = xall[DIM + tid];
  d_tile512(blk, tid, hs2p1, cw2, U, wl);
  __syncthreads();
  d_halo_attn(tid, U, xrow, w54);
  __syncthreads();
  d_conv512(tid, U, wl, cb2[0], Ao);
  d_gemm32(tid, Ao, U, WaT, ba, H2, 132, 0);
  __syncthreads();
  {
    float x0 = xall[2 * DIM + lane * 2], x1 = xall[2 * DIM + lane * 2 + 1];
    for (int rr = 0; rr < 4; ++rr) {
      int row = wv * 4 + rr;
      float2 h = *(const float2*)&H2[row * 132 + lane * 2];
      float p = h.x * x0 + h.y * x1;
      #pragma unroll
      for (int s = 32; s > 0; s >>= 1) p += __shfl_xor(p, s, 64);
      if (lane == 0) w54[row] = tanhf(p);
    }
  }
  __syncthreads();
  if (tid < DIM) {
    float s = 0.f;
    #pragma unroll
    for (int r = 0; r < 32; ++r) s += w54[r] * H2[r * 132 + tid];
    partialP[blk * DIM + tid] = s;
  }
  __threadfence();
  __syncthreads();
  if (tid == 0) lastf = (atomicAdd(ctr, 1) == (int)gridDim.x - 1);
  __syncthreads();
  if (lastf) {
    __threadfence();
    {
      int c = tid & 127, q = tid >> 7;
      float s = 0.f;
      for (int bb = q * 64; bb < q * 64 + 64; bb += 4)
        s += partialP[(bb + 0) * DIM + c] + partialP[(bb + 1) * DIM + c]
           + partialP[(bb + 2) * DIM + c] + partialP[(bb + 3) * DIM + c];
      red[q * DIM + c] = s;
    }
    __syncthreads();
    if (tid < DIM)
      xps[tid] = red[tid] + red[DIM + tid] + red[2 * DIM + tid] + red[3 * DIM + tid];
    __syncthreads();
    float p0 = 0.f, p1 = 0.f;
    if (tid < 256) {
      float y = (tid < DIM) ? xc[tid] : xps[tid - DIM];
      p0 = y * Wo[tid];
      p1 = y * Wo[256 + tid];
    }
    #pragma unroll
    for (int s = 32; s > 0; s >>= 1) {
      p0 += __shfl_xor(p0, s, 64);
      p1 += __shfl_xor(p1, s, 64);
    }
    if (tid < 256 && lane == 0) { fs[wv] = p0; fs[16 + wv] = p1; }
    __syncthreads();
    if (tid == 0) {
      float l0 = bo[0], l1 = bo[1];
      #pragma unroll
      for (int w = 0; w < 4; ++w) { l0 += fs[w]; l1 += fs[16 + w]; }
      float m = fmaxf(l0, l1);
      float e0 = expf(l0 - m), e1 = expf(l1 - m);
      out[0] = e0 / (e0 + e1);
      out[1] = e1 / (e0 + e1);
    }
  }
}

// ================= host =================
extern "C" void kernel_launch(void* const* d_in, const int* in_sizes, int n_in,
                              void* d_out, int out_size, void* d_ws, size_t ws_size,
                              hipStream_t stream) {
  const int*   fp     = (const int*)d_in[0];
  const int*   words  = (const int*)d_in[1];
  const float* adj    = (const float*)d_in[2];
  const float* emb_fp = (const float*)d_in[3];
  const float* emb_w  = (const float*)d_in[4];
  const float* Wg     = (const float*)d_in[5];
  const float* bg     = (const float*)d_in[6];
  const float* cw     = (const float*)d_in[7];
  const float* cb     = (const float*)d_in[8];
  const float* Wa     = (const float*)d_in[9];
  const float* ba     = (const float*)d_in[10];
  const float* Wo     = (const float*)d_in[11];
  const float* bo     = (const float*)d_in[12];
  float* out = (float*)d_out;

  float* ws    = (float*)d_ws;
  float* xs    = ws;                      // atom features (in place)
  float* bufB  = ws + (size_t)NF;         // hs0, then hs2p1
  float* bufC  = ws + 2 * (size_t)NF;     // xsp0, then hs1
  float* bufD  = ws + 3 * (size_t)NF;     // hs2p0
  int*   ell   = (int*)(ws + 4 * (size_t)NF);
  int*   cnt   = ell + (size_t)NA * CAP;
  int*   degcol= cnt + NA;
  int*   ctrs  = degcol + NA;             // [2]
  float* xc    = (float*)(ctrs + 2);      // [128]
  float* xall  = xc + DIM;                // [3,128]
  float* WgT   = xall + 3 * DIM;          // [3,128,128]
  float* WaT   = WgT + 3 * DIM * DIM;     // [128,128]
  float* partG = WaT + DIM * DIM;         // [256,128]
  float* partP = partG + 256 * DIM;       // [256,128]

  k_prep<<<dim3(2121), 256, 0, stream>>>(fp, words, emb_fp, emb_w, Wg, Wa,
                                         xs, bufC, WgT, WaT, degcol, ctrs);
  k_scan<<<dim3(1536), 512, 0, stream>>>(adj, xs, WgT, bg, bufB,
                                         bufC, cw, cb, WaT, ba, bufD,
                                         ell, cnt, degcol);
  k_spmv<<<dim3(NA / 4), 256, 0, stream>>>(ell, cnt, bufB, xs);
  k_gemm1<<<dim3(256), 256, 0, stream>>>(xs, WgT + (size_t)DIM * DIM,
                                         bg + DIM, bufC);
  k_spmv<<<dim3(NA / 4), 256, 0, stream>>>(ell, cnt, bufC, xs);
  k_g2fin<<<dim3(256), 256, 0, stream>>>(xs, WgT + 2 * (size_t)DIM * DIM,
                                         bg + 2 * DIM, degcol, partG, xc,
                                         WaT, ba, xall, ctrs);
  k_p1<<<dim3(256), 512, 0, stream>>>(bufD, xall, cw + 529, cb + 1, WaT, ba, bufB);
  k_p2<<<dim3(256), 512, 0, stream>>>(bufB, xall, cw + 2 * 529, cb + 2, WaT, ba,
                                      partP, xc, Wo, bo, out, ctrs + 1);
}